// Round 5
// baseline (244.043 us; speedup 1.0000x reference)
//
#include <hip/hip_runtime.h>

// SPN left-to-right propagation — pure-register single-wave formulation,
// with sched_barrier(0)-pinned prefetch pipeline.
//
// h[:,:,i,t] = (1-g1-g2-g3)*x[...,i,t] + g1*h[i-1,t-1] + g2*h[i,t-1] + g3*h[i+1,t-1]
// Gates: if |G1|+|G2|+|G3| >= 1, divide by the sum (EPS branch is dead code).
//
// Mapping: grid=256 (one (b,c) plane per block), block=64 = ONE wave.
// Lane l owns rows 4l..4l+3; cross-row coupling via 2 shfl per step.
// No LDS, no barriers, no global_load_lds.
//
// Round-4 lesson: traffic was ideal (257MB fetch / 67MB write) but
// VGPR_Count=220 < 256 staging regs proved the compiler SANK the prefetch
// loads to their uses, serializing ~430cy of HBM latency per 4-col quarter.
// Fix: __builtin_amdgcn_sched_barrier(0) after each QUARTER+LOADQ pair pins
// load issue ~3 quarters (~2000cy) before first use; last phase peeled so
// main-loop loads are unconditional. Fast rcp for the gate normalization
// (1-ulp v_rcp_f32; tolerance is 0.26, we're at 0.03).

#define HH 256
#define WW 256

#define EL(v, k) ((k) == 0 ? (v).x : ((k) == 1 ? (v).y : ((k) == 2 ? (v).z : (v).w)))
#define SETEL(v, k, val)                                                     \
    do {                                                                     \
        if ((k) == 0) (v).x = (val);                                         \
        else if ((k) == 1) (v).y = (val);                                    \
        else if ((k) == 2) (v).z = (val);                                    \
        else (v).w = (val);                                                  \
    } while (0)

#define FENCE() __builtin_amdgcn_sched_barrier(0)

extern "C" __global__ void __launch_bounds__(64, 1)
spn_lr_pin(const float* __restrict__ xg, const float* __restrict__ g1g,
           const float* __restrict__ g2g, const float* __restrict__ g3g,
           float* __restrict__ outg) {
    const int lane = threadIdx.x;  // owns rows 4*lane .. 4*lane+3
    const size_t off =
        (size_t)blockIdx.x * (size_t)(HH * WW) + (size_t)(4 * lane) * WW;
    const float* bx = xg + off;
    const float* b1 = g1g + off;
    const float* b2 = g2g + off;
    const float* b3 = g3g + off;
    float* bo = outg + off;

    // Staging: [row][quarter] float4 per array = 256 VGPRs. Static idx only.
    float4 Sx[4][4], S1[4][4], S2[4][4], S3[4][4];
    float4 o[4][4];  // output accumulator [row][quarter]

    // ---- prologue: load group 0 (16 cols x 4 rows x 4 arrays) ----
#pragma unroll
    for (int r = 0; r < 4; ++r) {
#pragma unroll
        for (int c = 0; c < 4; ++c) {
            Sx[r][c] = *reinterpret_cast<const float4*>(bx + r * WW + c * 4);
            S1[r][c] = *reinterpret_cast<const float4*>(b1 + r * WW + c * 4);
            S2[r][c] = *reinterpret_cast<const float4*>(b2 + r * WW + c * 4);
            S3[r][c] = *reinterpret_cast<const float4*>(b3 + r * WW + c * 4);
        }
    }
    FENCE();

    float h0 = 0.0f, h1 = 0.0f, h2 = 0.0f, h3 = 0.0f;

#define ROWC(RA, HU, HC, HD, NV, C4, K)                                       \
    do {                                                                      \
        float A1 = EL(S1[RA][C4], K);                                         \
        float A2 = EL(S2[RA][C4], K);                                         \
        float A3 = EL(S3[RA][C4], K);                                         \
        const float sa = fabsf(A1) + fabsf(A2) + fabsf(A3);                   \
        const float inv = (sa >= 1.0f) ? __builtin_amdgcn_rcpf(sa) : 1.0f;    \
        A1 *= inv; A2 *= inv; A3 *= inv;                                      \
        const float d = (1.0f - A1 - A2 - A3) * EL(Sx[RA][C4], K);            \
        NV = fmaf(A1, HU, fmaf(A2, HC, fmaf(A3, HD, d)));                     \
    } while (0)

#define STEP(C4, K)                                                           \
    do {                                                                      \
        float up = __shfl_up(h3, 1);                                          \
        float dn = __shfl_down(h0, 1);                                        \
        if (lane == 0) up = 0.0f;                                             \
        if (lane == 63) dn = 0.0f;                                            \
        float n0, n1, n2, n3;                                                 \
        ROWC(0, up, h0, h1, n0, C4, K);                                       \
        ROWC(1, h0, h1, h2, n1, C4, K);                                       \
        ROWC(2, h1, h2, h3, n2, C4, K);                                       \
        ROWC(3, h2, h3, dn, n3, C4, K);                                       \
        h0 = n0; h1 = n1; h2 = n2; h3 = n3;                                   \
        SETEL(o[0][C4], K, n0);                                               \
        SETEL(o[1][C4], K, n1);                                               \
        SETEL(o[2][C4], K, n2);                                               \
        SETEL(o[3][C4], K, n3);                                               \
    } while (0)

#define QUARTER(C4)                                                           \
    do { STEP(C4, 0); STEP(C4, 1); STEP(C4, 2); STEP(C4, 3); } while (0)

    // Refill quarter C4 from the NEXT group (base+16). First use is next
    // phase's QUARTER(C4), 4 quarters (~2000cy) away. FENCE after pins it.
#define LOADQ(C4)                                                             \
    do {                                                                      \
        _Pragma("unroll") for (int r_ = 0; r_ < 4; ++r_) {                    \
            Sx[r_][C4] = *reinterpret_cast<const float4*>(                    \
                bx + 16 + r_ * WW + (C4) * 4);                                \
            S1[r_][C4] = *reinterpret_cast<const float4*>(                    \
                b1 + 16 + r_ * WW + (C4) * 4);                                \
            S2[r_][C4] = *reinterpret_cast<const float4*>(                    \
                b2 + 16 + r_ * WW + (C4) * 4);                                \
            S3[r_][C4] = *reinterpret_cast<const float4*>(                    \
                b3 + 16 + r_ * WW + (C4) * 4);                                \
        }                                                                     \
    } while (0)

#define STOREPHASE()                                                          \
    do {                                                                      \
        _Pragma("unroll") for (int r_ = 0; r_ < 4; ++r_) {                    \
            _Pragma("unroll") for (int c_ = 0; c_ < 4; ++c_) {                \
                *reinterpret_cast<float4*>(bo + r_ * WW + c_ * 4) = o[r_][c_];\
            }                                                                 \
        }                                                                     \
    } while (0)

    // ---- main loop: 15 phases with prefetch, unconditional loads ----
#pragma unroll 1
    for (int p = 0; p < 15; ++p) {
        QUARTER(0); LOADQ(0); FENCE();
        QUARTER(1); LOADQ(1); FENCE();
        QUARTER(2); LOADQ(2); FENCE();
        QUARTER(3); LOADQ(3); FENCE();
        STOREPHASE();
        bx += 16; b1 += 16; b2 += 16; b3 += 16; bo += 16;
    }

    // ---- epilogue: phase 15, no prefetch ----
    QUARTER(0);
    QUARTER(1);
    QUARTER(2);
    QUARTER(3);
    STOREPHASE();

#undef STOREPHASE
#undef LOADQ
#undef QUARTER
#undef STEP
#undef ROWC
}

extern "C" void kernel_launch(void* const* d_in, const int* in_sizes, int n_in,
                              void* d_out, int out_size, void* d_ws, size_t ws_size,
                              hipStream_t stream) {
    const float* x  = (const float*)d_in[0];
    const float* G1 = (const float*)d_in[1];
    const float* G2 = (const float*)d_in[2];
    const float* G3 = (const float*)d_in[3];
    float* out = (float*)d_out;

    const int nplanes = in_sizes[0] / (HH * WW);  // B*C = 256
    spn_lr_pin<<<dim3(nplanes), dim3(64), 0, stream>>>(x, G1, G2, G3, out);
}

// Round 6
// 159.107 us; speedup vs baseline: 1.5338x; 1.5338x over previous
//
#include <hip/hip_runtime.h>

// SPN left-to-right propagation — pure-register single-wave, ring-of-3
// fenced prefetch pipeline sized to the 256-arch-VGPR ceiling.
//
// h[:,:,i,t] = (1-g1-g2-g3)*x[...,i,t] + g1*h[i-1,t-1] + g2*h[i,t-1] + g3*h[i+1,t-1]
// Gates: if |G1|+|G2|+|G3| >= 1, divide by the sum (EPS branch dead).
//
// Mapping: grid=256 planes, block=64 = ONE wave, lane owns rows 4l..4l+3,
// neighbor h via 2 shfl/step. No LDS, no barriers.
//
// Lessons baked in:
//  r2: partial-line consumption w/ L2 thrash = 4x overfetch -> every line
//      consumed by its fetching lane, same phase.
//  r4: unfenced prefetch -> compiler sinks loads to uses (latency serial).
//  r5: fenced D=4 needs 256 staging VGPRs -> arch-VGPR cap is 256 (not 450;
//      512 is the unified VGPR+AGPR pool) -> scratch spills (WRITE 67->183MB).
// Fix: ring-3 quarter buffers = 192 staging regs; consume->store->reload->
// sched_barrier(0) per region; quarter stored immediately (no 64-reg out
// accumulator; round-2 counters showed no write-allocate-fetch, and with a
// ~2MB/XCD L2 live set the 4 stores per 64B line merge before eviction).

#define HH 256
#define WW 256

#define EL(v, k) ((k) == 0 ? (v).x : ((k) == 1 ? (v).y : ((k) == 2 ? (v).z : (v).w)))
#define SETEL(v, k, val)                                                     \
    do {                                                                     \
        if ((k) == 0) (v).x = (val);                                         \
        else if ((k) == 1) (v).y = (val);                                    \
        else if ((k) == 2) (v).z = (val);                                    \
        else (v).w = (val);                                                  \
    } while (0)

#define FENCE() __builtin_amdgcn_sched_barrier(0)

extern "C" __global__ void __launch_bounds__(64, 1)
spn_lr_r3(const float* __restrict__ xg, const float* __restrict__ g1g,
          const float* __restrict__ g2g, const float* __restrict__ g3g,
          float* __restrict__ outg) {
    const int lane = threadIdx.x;  // owns rows 4*lane .. 4*lane+3
    const size_t off =
        (size_t)blockIdx.x * (size_t)(HH * WW) + (size_t)(4 * lane) * WW;
    const float4* px = reinterpret_cast<const float4*>(xg + off);
    const float4* p1 = reinterpret_cast<const float4*>(g1g + off);
    const float4* p2 = reinterpret_cast<const float4*>(g2g + off);
    const float4* p3 = reinterpret_cast<const float4*>(g3g + off);
    float4* po = reinterpret_cast<float4*>(outg + off);
    // row r, quarter q  ->  f4 index r*(WW/4) + q

    // Ring of 3 quarter-buffers: [row] float4 per array. 3*16 f4 = 192 VGPRs.
    float4 Sx_0[4], S1_0[4], S2_0[4], S3_0[4];
    float4 Sx_1[4], S1_1[4], S2_1[4], S3_1[4];
    float4 Sx_2[4], S1_2[4], S2_2[4], S3_2[4];

#define LOADQ(B, Q)                                                           \
    do {                                                                      \
        _Pragma("unroll") for (int r_ = 0; r_ < 4; ++r_) {                    \
            Sx_##B[r_] = px[r_ * (WW / 4) + (Q)];                             \
            S1_##B[r_] = p1[r_ * (WW / 4) + (Q)];                             \
            S2_##B[r_] = p2[r_ * (WW / 4) + (Q)];                             \
            S3_##B[r_] = p3[r_ * (WW / 4) + (Q)];                             \
        }                                                                     \
    } while (0)

    // One row's normalize + recurrence for element k of the buffer.
#define ROWC(B, RA, HU, HC, HD, NV, K)                                        \
    do {                                                                      \
        float A1 = EL(S1_##B[RA], K);                                         \
        float A2 = EL(S2_##B[RA], K);                                         \
        float A3 = EL(S3_##B[RA], K);                                         \
        const float sa = fabsf(A1) + fabsf(A2) + fabsf(A3);                   \
        const float inv = (sa >= 1.0f) ? __builtin_amdgcn_rcpf(sa) : 1.0f;    \
        A1 *= inv; A2 *= inv; A3 *= inv;                                      \
        const float d = (1.0f - A1 - A2 - A3) * EL(Sx_##B[RA], K);            \
        NV = fmaf(A1, HU, fmaf(A2, HC, fmaf(A3, HD, d)));                     \
    } while (0)

    // Region: consume buffer B (= quarter Q), store, reload B <- Q+3, fence.
#define REGION(B, Q, DOLOAD)                                                  \
    do {                                                                      \
        float4 out_[4];                                                       \
        _Pragma("unroll") for (int k_ = 0; k_ < 4; ++k_) {                    \
            float up_ = __shfl_up(h3, 1);                                     \
            float dn_ = __shfl_down(h0, 1);                                   \
            if (lane == 0) up_ = 0.0f;                                        \
            if (lane == 63) dn_ = 0.0f;                                       \
            float n0_, n1_, n2_, n3_;                                         \
            ROWC(B, 0, up_, h0, h1, n0_, k_);                                 \
            ROWC(B, 1, h0, h1, h2, n1_, k_);                                  \
            ROWC(B, 2, h1, h2, h3, n2_, k_);                                  \
            ROWC(B, 3, h2, h3, dn_, n3_, k_);                                 \
            h0 = n0_; h1 = n1_; h2 = n2_; h3 = n3_;                           \
            SETEL(out_[0], k_, n0_);                                          \
            SETEL(out_[1], k_, n1_);                                          \
            SETEL(out_[2], k_, n2_);                                          \
            SETEL(out_[3], k_, n3_);                                          \
        }                                                                     \
        _Pragma("unroll") for (int r_ = 0; r_ < 4; ++r_) {                    \
            po[r_ * (WW / 4) + (Q)] = out_[r_];                               \
        }                                                                     \
        if (DOLOAD) LOADQ(B, (Q) + 3);                                        \
        FENCE();                                                              \
    } while (0)

    // ---- prologue: fill the ring with quarters 0,1,2 ----
    LOADQ(0, 0);
    LOADQ(1, 1);
    LOADQ(2, 2);
    FENCE();

    float h0 = 0.0f, h1 = 0.0f, h2 = 0.0f, h3 = 0.0f;

    // ---- main loop: quarters 0..59, loads reach 62 ----
#pragma unroll 1
    for (int t = 0; t < 20; ++t) {
        const int q = 3 * t;
        REGION(0, q + 0, true);
        REGION(1, q + 1, true);
        REGION(2, q + 2, true);
    }

    // ---- epilogue: quarters 60..63 (60 loads 63 into buf0; 63%3==0) ----
    REGION(0, 60, true);
    REGION(1, 61, false);
    REGION(2, 62, false);
    REGION(0, 63, false);

#undef REGION
#undef ROWC
#undef LOADQ
}

extern "C" void kernel_launch(void* const* d_in, const int* in_sizes, int n_in,
                              void* d_out, int out_size, void* d_ws, size_t ws_size,
                              hipStream_t stream) {
    const float* x  = (const float*)d_in[0];
    const float* G1 = (const float*)d_in[1];
    const float* G2 = (const float*)d_in[2];
    const float* G3 = (const float*)d_in[3];
    float* out = (float*)d_out;

    const int nplanes = in_sizes[0] / (HH * WW);  // B*C = 256
    spn_lr_r3<<<dim3(nplanes), dim3(64), 0, stream>>>(x, G1, G2, G3, out);
}

// Round 8
// 111.376 us; speedup vs baseline: 2.1912x; 1.4286x over previous
//
#include <hip/hip_runtime.h>

// SPN left-to-right propagation — 4-wave, K=4 column-halo formulation.
//
// h[:,:,i,t] = (1-g1-g2-g3)*x[...,i,t] + g1*h[i-1,t-1] + g2*h[i,t-1] + g3*h[i+1,t-1]
// Gates: if |G1|+|G2|+|G3| >= 1, divide by the sum (EPS branch is dead code).
//
// Design (from r1..r7 counters):
//  * 16B-scattered VMEM is request-rate poison (r4/r6: 16M L2 requests ->
//    ~160us). ALL global traffic moves as grouped 64B lines: 4 consecutive
//    float4 loads per (array,row) every 4th iter (L1 absorbs 3/4 touches,
//    r1-proven: 260MB FETCH), full-line stores every 4th iter.
//  * r1's other binder was 256 barrier round-trips (~940cy/step). Fix:
//    advance 4 columns per barrier with halo-redundant compute: read 9
//    neighbor h, compute shrinking band 7+5+3+1 = 16 rowcalcs / 4 cols.
//  * Neighbor coefficients via LDS, pre-normalized at stage time, stored as
//    float4(d,g1,g2,g3) in [3][256][5][4] (triple buffer, 61.4KB): row
//    stride 20 f32 -> bank-quad (5r+j)%8 spans all 8 quads across lanes ->
//    ds_read_b128 at the structural floor, conflict-free. Triple-buffering
//    makes ONE raw barrier per 4-col iteration sufficient (buf b's readers
//    finished before the barrier that precedes b's next overwrite).
//  * Raw s_barrier + lgkmcnt(0) only: global prefetch stays in flight.
//
// r7 bug (absmax 2.7): HROW's HIGH pads live at indices HH+4..HH+7 (layout
// is HROW[b][4+j] = row j), but init zeroed HH+s-4 = 256..259 -> real pads
// held stale LDS garbage, leaking g3*garbage into rows 252..255. Fixed:
// zero HH+s = 260..263.

#define HH 256
#define WW 256

#define EL(v, k) ((k) == 0 ? (v).x : ((k) == 1 ? (v).y : ((k) == 2 ? (v).z : (v).w)))

extern "C" __global__ void __launch_bounds__(256, 1)
spn_halo4(const float* __restrict__ xg, const float* __restrict__ g1g,
          const float* __restrict__ g2g, const float* __restrict__ g3g,
          float* __restrict__ outg) {
    const int i = threadIdx.x;  // row index
    const size_t off = (size_t)blockIdx.x * (size_t)(HH * WW) + (size_t)i * WW;
    const float4* px = reinterpret_cast<const float4*>(xg + off);
    const float4* p1 = reinterpret_cast<const float4*>(g1g + off);
    const float4* p2 = reinterpret_cast<const float4*>(g2g + off);
    const float4* p3 = reinterpret_cast<const float4*>(g3g + off);
    float4* po = reinterpret_cast<float4*>(outg + off);

    __shared__ float COEF[3][HH][5][4];  // [buf][row][colslot(4+1 pad)][d,g1,g2,g3]
    __shared__ float HROW[2][HH + 8];    // h exchange, 4-wide zero pads each side

    if (i < 16) {  // zero pads of both h buffers: slots 0..3 and HH+4..HH+7
        const int b = i >> 3, s = i & 7;
        HROW[b][(s < 4) ? s : (HH + s)] = 0.0f;
    }

    // Per-thread constants: validity + clamped row offsets (f32 units, row stride 20)
    bool vmsk[9];
    int roff[9];
#pragma unroll
    for (int d = 0; d < 9; ++d) {
        const int r = i - 4 + d;
        vmsk[d] = (r >= 0) && (r < HH);
        const int rc = r < 0 ? 0 : (r > HH - 1 ? HH - 1 : r);
        roff[d] = rc * 20;
    }

    // Raw line-group staging: [array][q] = 16 cols per group, full 64B lines.
    float4 Ax[4], A1[4], A2[4], A3[4];
    float4 Bx[4], B1[4], B2[4], B3[4];

#define LOADG(GX, G1_, G2_, G3_, T)                                           \
    do {                                                                      \
        _Pragma("unroll") for (int q_ = 0; q_ < 4; ++q_) {                    \
            GX[q_] = px[(T) * 4 + q_];                                        \
            G1_[q_] = p1[(T) * 4 + q_];                                       \
            G2_[q_] = p2[(T) * 4 + q_];                                       \
            G3_[q_] = p3[(T) * 4 + q_];                                       \
        }                                                                     \
    } while (0)

    // Normalize 4-col chunk Q of a raw group; write float4(d,g1,g2,g3) rows.
#define NORMW(GX, G1_, G2_, G3_, Q)                                           \
    do {                                                                      \
        float* wb_ = &COEF[0][0][0][0] + cbn * (HH * 20) + i * 20;            \
        _Pragma("unroll") for (int k_ = 0; k_ < 4; ++k_) {                    \
            float a1 = EL(G1_[Q], k_);                                        \
            float a2 = EL(G2_[Q], k_);                                        \
            float a3 = EL(G3_[Q], k_);                                        \
            const float sa = fabsf(a1) + fabsf(a2) + fabsf(a3);               \
            const float inv = (sa >= 1.0f) ? __builtin_amdgcn_rcpf(sa) : 1.0f;\
            a1 *= inv; a2 *= inv; a3 *= inv;                                  \
            const float dd = (1.0f - a1 - a2 - a3) * EL(GX[Q], k_);           \
            *reinterpret_cast<float4*>(wb_ + k_ * 4) =                        \
                make_float4(dd, a1, a2, a3);                                  \
        }                                                                     \
    } while (0)

    // One 4-col iteration. P = c%4 (literal). Norm source regs passed in.
#define ITER(P, DONORM, NGX, NG1, NG2, NG3, NQ)                               \
    do {                                                                      \
        HROW[(P) & 1][4 + i] = h;                                             \
        if (DONORM) NORMW(NGX, NG1, NG2, NG3, NQ);                            \
        asm volatile("s_waitcnt lgkmcnt(0)" ::: "memory");                    \
        __builtin_amdgcn_s_barrier();                                         \
        asm volatile("" ::: "memory");                                        \
        float hh[9];                                                          \
        _Pragma("unroll") for (int d_ = 0; d_ < 9; ++d_)                      \
            hh[d_] = HROW[(P) & 1][i + d_];                                   \
        const float* cb_ = &COEF[0][0][0][0] + cbc * (HH * 20);               \
        float n1[9], n2[9], n3[9], own3;                                      \
        _Pragma("unroll") for (int d_ = 1; d_ < 8; ++d_) {                    \
            const float4 cf =                                                 \
                *reinterpret_cast<const float4*>(cb_ + roff[d_]);             \
            const float v = fmaf(cf.y, hh[d_ - 1],                            \
                            fmaf(cf.z, hh[d_],                                \
                            fmaf(cf.w, hh[d_ + 1], cf.x)));                   \
            n1[d_] = vmsk[d_] ? v : 0.0f;                                     \
        }                                                                     \
        _Pragma("unroll") for (int d_ = 2; d_ < 7; ++d_) {                    \
            const float4 cf =                                                 \
                *reinterpret_cast<const float4*>(cb_ + roff[d_] + 4);         \
            const float v = fmaf(cf.y, n1[d_ - 1],                            \
                            fmaf(cf.z, n1[d_],                                \
                            fmaf(cf.w, n1[d_ + 1], cf.x)));                   \
            n2[d_] = vmsk[d_] ? v : 0.0f;                                     \
        }                                                                     \
        _Pragma("unroll") for (int d_ = 3; d_ < 6; ++d_) {                    \
            const float4 cf =                                                 \
                *reinterpret_cast<const float4*>(cb_ + roff[d_] + 8);         \
            const float v = fmaf(cf.y, n2[d_ - 1],                            \
                            fmaf(cf.z, n2[d_],                                \
                            fmaf(cf.w, n2[d_ + 1], cf.x)));                   \
            n3[d_] = vmsk[d_] ? v : 0.0f;                                     \
        }                                                                     \
        {                                                                     \
            const float4 cf =                                                 \
                *reinterpret_cast<const float4*>(cb_ + roff[4] + 12);         \
            own3 = fmaf(cf.y, n3[3],                                          \
                   fmaf(cf.z, n3[4],                                          \
                   fmaf(cf.w, n3[5], cf.x)));                                 \
        }                                                                     \
        o##P = make_float4(n1[4], n2[4], n3[4], own3);                        \
        h = own3;                                                             \
        cbc = cbn;                                                            \
        cbn = (cbn == 2) ? 0 : cbn + 1;                                       \
    } while (0)

    // One line-group = 4 iterations (16 cols). CUR holds this group's raw
    // data; NXT gets the prefetch for group t+1 (issued after ITER 0 so it
    // has ~3 iterations to land before ITER(3)'s NORMW consumes NXT[0]).
#define GROUP(CX, C1, C2, C3, NX, N1, N2, N3)                                 \
    do {                                                                      \
        ITER(0, true, CX, C1, C2, C3, 1);                                     \
        if (t < 15) LOADG(NX, N1, N2, N3, t + 1);                             \
        ITER(1, true, CX, C1, C2, C3, 2);                                     \
        ITER(2, true, CX, C1, C2, C3, 3);                                     \
        const bool dn_ = (t < 15);                                            \
        ITER(3, dn_, NX, N1, N2, N3, 0);                                      \
        po[t * 4 + 0] = o0;                                                   \
        po[t * 4 + 1] = o1;                                                   \
        po[t * 4 + 2] = o2;                                                   \
        po[t * 4 + 3] = o3;                                                   \
        ++t;                                                                  \
    } while (0)

    // ---- prologue ----
    LOADG(Ax, A1, A2, A3, 0);
    int cbc = 0, cbn = 0;
    float h = 0.0f;
    NORMW(Ax, A1, A2, A3, 0);  // chunk 0 -> buffer 0
    cbn = 1;
    float4 o0, o1, o2, o3;
    int t = 0;

    // ---- main: 16 groups of 16 cols; A/B ping-pong, no register copies ----
#pragma unroll 1
    for (int tt = 0; tt < 8; ++tt) {
        GROUP(Ax, A1, A2, A3, Bx, B1, B2, B3);
        GROUP(Bx, B1, B2, B3, Ax, A1, A2, A3);
    }

#undef GROUP
#undef ITER
#undef NORMW
#undef LOADG
}

extern "C" void kernel_launch(void* const* d_in, const int* in_sizes, int n_in,
                              void* d_out, int out_size, void* d_ws, size_t ws_size,
                              hipStream_t stream) {
    const float* x  = (const float*)d_in[0];
    const float* G1 = (const float*)d_in[1];
    const float* G2 = (const float*)d_in[2];
    const float* G3 = (const float*)d_in[3];
    float* out = (float*)d_out;

    const int nplanes = in_sizes[0] / (HH * WW);  // B*C = 256
    spn_halo4<<<dim3(nplanes), dim3(HH), 0, stream>>>(x, G1, G2, G3, out);
}